// Round 1
// baseline (974.905 us; speedup 1.0000x reference)
//
#include <hip/hip_runtime.h>
#include <math.h>

// Problem constants
#define BATCH   8192
#define IN_DIM  1024
#define LAT     256
#define NEMB    8192

// ---------------------------------------------------------------------------
// Generic NT GEMM: C[M][N] = A[M][K] @ Bw[N][K]^T + bias[N]
// 64x64 tile, 256 threads, 4x4 micro-tile, K-slices of 64.
// LDS pitch 68 (=64+4): float4 reads are 16B aligned, bank stride 4 -> 2-way
// conflicts only (free on gfx950 per measured m136).
// ---------------------------------------------------------------------------
#define TS 64
#define KSL 64

__global__ __launch_bounds__(256) void gemm_nt(
    const float* __restrict__ A, const float* __restrict__ Bw,
    const float* __restrict__ bias, float* __restrict__ C,
    int M, int N, int K) {
  __shared__ float a_s[TS][KSL + 4];
  __shared__ float b_s[TS][KSL + 4];
  const int tid = threadIdx.x;
  const int tx = tid & 15, ty = tid >> 4;
  const int rb = blockIdx.y * TS;
  const int cb = blockIdx.x * TS;

  float acc[4][4] = {};

  for (int ks = 0; ks < K; ks += KSL) {
    // stage: 64x64 floats = 1024 float4 per tile, 4 per thread
#pragma unroll
    for (int t = 0; t < 4; ++t) {
      int flat = t * 256 + tid;       // 0..1023
      int r = flat >> 4;              // 0..63
      int c4 = flat & 15;             // 0..15
      float4 av = *(const float4*)&A[(size_t)(rb + r) * K + ks + 4 * c4];
      *(float4*)&a_s[r][4 * c4] = av;
      float4 bv = *(const float4*)&Bw[(size_t)(cb + r) * K + ks + 4 * c4];
      *(float4*)&b_s[r][4 * c4] = bv;
    }
    __syncthreads();
#pragma unroll 4
    for (int kk = 0; kk < KSL; kk += 4) {
      float4 a4[4], b4[4];
#pragma unroll
      for (int i = 0; i < 4; ++i) a4[i] = *(const float4*)&a_s[ty + 16 * i][kk];
#pragma unroll
      for (int j = 0; j < 4; ++j) b4[j] = *(const float4*)&b_s[tx + 16 * j][kk];
#pragma unroll
      for (int i = 0; i < 4; ++i)
#pragma unroll
        for (int j = 0; j < 4; ++j)
          acc[i][j] += a4[i].x * b4[j].x + a4[i].y * b4[j].y +
                       a4[i].z * b4[j].z + a4[i].w * b4[j].w;
    }
    __syncthreads();
  }

#pragma unroll
  for (int i = 0; i < 4; ++i) {
    int r = rb + ty + 16 * i;
#pragma unroll
    for (int j = 0; j < 4; ++j) {
      int c = cb + tx + 16 * j;
      C[(size_t)r * N + c] = acc[i][j] + bias[c];
    }
  }
}

// ---------------------------------------------------------------------------
// Per-code inverse norms: one wave per embedding row.
// ---------------------------------------------------------------------------
__global__ __launch_bounds__(256) void emb_norms(
    const float* __restrict__ emb, float* __restrict__ inv_norm) {
  int row = blockIdx.x * 4 + (threadIdx.x >> 6);
  int lane = threadIdx.x & 63;
  const float* p = emb + (size_t)row * LAT;
  float s = 0.f;
#pragma unroll
  for (int t = 0; t < 4; ++t) {
    float v = p[lane + 64 * t];
    s += v * v;
  }
#pragma unroll
  for (int off = 32; off; off >>= 1) s += __shfl_xor(s, off);
  if (lane == 0) inv_norm[row] = 1.0f / sqrtf(s);
}

// ---------------------------------------------------------------------------
// Fused score GEMM + row argmax.
// Block: 32 batch rows x 4096 codes (grid = 256 row-blocks x 2 code-splits).
// z tile (32 x 256, pitch 260) resident in LDS for the whole block;
// emb chunk (128 codes x 64-K slice, pitch 68) streamed.
// Per-thread 2x8 micro-tile. Partial (score,idx) combined across code-splits
// with an order-preserving packed u64 atomicMax; ties resolve to lowest idx
// (np.argmin semantics).
// ---------------------------------------------------------------------------
#define SR 32
#define SCC 128
#define SKS 64
#define CPB 4096

__global__ __launch_bounds__(256) void score_argmax(
    const float* __restrict__ z, const float* __restrict__ emb,
    const float* __restrict__ inv_norm,
    unsigned long long* __restrict__ packed) {
  __shared__ float z_s[SR][260];
  __shared__ float e_s[SCC][SKS + 4];
  const int tid = threadIdx.x;
  const int tx = tid & 15, ty = tid >> 4;
  const int rb = blockIdx.y * SR;
  const int c_base = blockIdx.x * CPB;

  // stage z rows (32*256 = 2048 float4, 8 per thread)
#pragma unroll
  for (int t = 0; t < 8; ++t) {
    int flat = t * 256 + tid;   // 0..2047
    int r = flat >> 6;          // 0..31
    int c4 = flat & 63;         // 0..63
    *(float4*)&z_s[r][4 * c4] =
        *(const float4*)&z[(size_t)(rb + r) * LAT + 4 * c4];
  }
  __syncthreads();

  float best[2] = {-INFINITY, -INFINITY};
  int bidx[2] = {0, 0};

  for (int c0 = 0; c0 < CPB; c0 += SCC) {
    float acc[2][8] = {};
    for (int ks = 0; ks < LAT; ks += SKS) {
      // stage emb chunk slice: 128 x 64 floats = 2048 float4, 8 per thread
#pragma unroll
      for (int t = 0; t < 8; ++t) {
        int flat = t * 256 + tid;
        int r = flat >> 4;      // 0..127
        int c4 = flat & 15;     // 0..15
        *(float4*)&e_s[r][4 * c4] =
            *(const float4*)&emb[(size_t)(c_base + c0 + r) * LAT + ks + 4 * c4];
      }
      __syncthreads();
#pragma unroll 4
      for (int kk = 0; kk < SKS; kk += 4) {
        float4 z4[2], e4[8];
        z4[0] = *(const float4*)&z_s[ty][ks + kk];
        z4[1] = *(const float4*)&z_s[ty + 16][ks + kk];
#pragma unroll
        for (int j = 0; j < 8; ++j)
          e4[j] = *(const float4*)&e_s[tx + 16 * j][kk];
#pragma unroll
        for (int i = 0; i < 2; ++i)
#pragma unroll
          for (int j = 0; j < 8; ++j)
            acc[i][j] += z4[i].x * e4[j].x + z4[i].y * e4[j].y +
                         z4[i].z * e4[j].z + z4[i].w * e4[j].w;
      }
      __syncthreads();
    }
    // fold this 128-code chunk into the running best
#pragma unroll
    for (int j = 0; j < 8; ++j) {
      int c = c_base + c0 + tx + 16 * j;
      float inv = inv_norm[c];
#pragma unroll
      for (int i = 0; i < 2; ++i) {
        float s = acc[i][j] * inv;
        if (s > best[i] || (s == best[i] && c < bidx[i])) {
          best[i] = s;
          bidx[i] = c;
        }
      }
    }
  }

  // reduce across the 16 tx lanes sharing each row (lanes differ in low 4 bits)
#pragma unroll
  for (int i = 0; i < 2; ++i) {
    float b = best[i];
    int bi = bidx[i];
#pragma unroll
    for (int off = 1; off < 16; off <<= 1) {
      float ob = __shfl_xor(b, off);
      int obi = __shfl_xor(bi, off);
      if (ob > b || (ob == b && obi < bi)) {
        b = ob;
        bi = obi;
      }
    }
    if (tx == 0) {
      unsigned int ub = __float_as_uint(b);
      ub = (ub & 0x80000000u) ? ~ub : (ub | 0x80000000u);  // order-preserving
      unsigned long long p =
          ((unsigned long long)ub << 32) |
          (unsigned long long)(unsigned int)(NEMB - 1 - bi);  // ties -> low idx
      atomicMax(&packed[rb + ty + 16 * i], p);
    }
  }
}

// ---------------------------------------------------------------------------
// Unpack idx, write idx as float, gather z_q = emb[idx]. One wave per row.
// ---------------------------------------------------------------------------
__global__ __launch_bounds__(256) void finalize(
    const unsigned long long* __restrict__ packed,
    const float* __restrict__ emb, float* __restrict__ zq,
    float* __restrict__ idx_out) {
  int row = blockIdx.x * 4 + (threadIdx.x >> 6);
  int lane = threadIdx.x & 63;
  unsigned long long p = packed[row];
  int idx = NEMB - 1 - (int)(p & 0xFFFFFFFFull);
  if (lane == 0) idx_out[row] = (float)idx;
  const float4* src = (const float4*)(emb + (size_t)idx * LAT);
  float4* dst = (float4*)(zq + (size_t)row * LAT);
  dst[lane] = src[lane];  // 64 lanes x 16B = one 256-float row
}

// ---------------------------------------------------------------------------
extern "C" void kernel_launch(void* const* d_in, const int* in_sizes, int n_in,
                              void* d_out, int out_size, void* d_ws,
                              size_t ws_size, hipStream_t stream) {
  (void)in_sizes; (void)n_in; (void)out_size; (void)ws_size;
  const float* x     = (const float*)d_in[0];
  const float* enc_w = (const float*)d_in[1];
  const float* enc_b = (const float*)d_in[2];
  const float* emb   = (const float*)d_in[3];
  const float* dec_w = (const float*)d_in[4];
  const float* dec_b = (const float*)d_in[5];

  float* out     = (float*)d_out;
  float* x_recon = out;                                   // 8192*1024
  float* z_out   = x_recon + (size_t)BATCH * IN_DIM;      // 8192*256
  float* zq_out  = z_out + (size_t)BATCH * LAT;           // 8192*256
  float* idx_out = zq_out + (size_t)BATCH * LAT;          // 8192 (as float)

  float* inv_norm = (float*)d_ws;                         // 8192 floats
  unsigned long long* packed =
      (unsigned long long*)((char*)d_ws + 65536);         // 8192 u64, aligned

  // 1. codebook inverse norms
  emb_norms<<<NEMB / 4, 256, 0, stream>>>(emb, inv_norm);

  // 2. encoder: z = x @ enc_w^T + enc_b
  gemm_nt<<<dim3(LAT / TS, BATCH / TS), 256, 0, stream>>>(
      x, enc_w, enc_b, z_out, BATCH, LAT, IN_DIM);

  // 3. zero argmax accumulators (any real packed score > 0)
  hipMemsetAsync(packed, 0, (size_t)BATCH * sizeof(unsigned long long), stream);

  // 4. fused score + argmax
  score_argmax<<<dim3(NEMB / CPB, BATCH / SR), 256, 0, stream>>>(
      z_out, emb, inv_norm, packed);

  // 5. idx + gather z_q
  finalize<<<BATCH / 4, 256, 0, stream>>>(packed, emb, zq_out, idx_out);

  // 6. decoder: x_recon = z_q @ dec_w^T + dec_b
  gemm_nt<<<dim3(IN_DIM / TS, BATCH / TS), 256, 0, stream>>>(
      zq_out, dec_w, dec_b, x_recon, BATCH, IN_DIM, LAT);
}

// Round 2
// 448.237 us; speedup vs baseline: 2.1750x; 2.1750x over previous
//
#include <hip/hip_runtime.h>
#include <math.h>

// Problem constants
#define BATCH   8192
#define IN_DIM  1024
#define LAT     256
#define NEMB    8192

#define TAU 1e-3f   // margin below which we exact-rescore (worst-case approx err <= 2e-4)

typedef __bf16 bf16x8_t __attribute__((ext_vector_type(8)));
typedef float f32x16_t __attribute__((ext_vector_type(16)));

typedef __attribute__((address_space(1))) const unsigned int gu32_t;
typedef __attribute__((address_space(3))) unsigned int lu32_t;

// order-preserving float<->u32 transform (monotone: a<b  <=>  ford(a)<ford(b))
__device__ __forceinline__ unsigned int ford(float x) {
  unsigned int u = __float_as_uint(x);
  return (u & 0x80000000u) ? ~u : (u | 0x80000000u);
}
__device__ __forceinline__ float funord(unsigned int t) {
  unsigned int u = (t & 0x80000000u) ? (t & 0x7FFFFFFFu) : ~t;
  return __uint_as_float(u);
}

// ---------------------------------------------------------------------------
// fp32 NT GEMM (encoder / decoder): C[M][N] = A[M][K] @ Bw[N][K]^T + bias[N]
// ---------------------------------------------------------------------------
#define TS 64
#define KSL 64

__global__ __launch_bounds__(256) void gemm_nt(
    const float* __restrict__ A, const float* __restrict__ Bw,
    const float* __restrict__ bias, float* __restrict__ C,
    int M, int N, int K) {
  __shared__ float a_s[TS][KSL + 4];
  __shared__ float b_s[TS][KSL + 4];
  const int tid = threadIdx.x;
  const int tx = tid & 15, ty = tid >> 4;
  const int rb = blockIdx.y * TS;
  const int cb = blockIdx.x * TS;

  float acc[4][4] = {};

  for (int ks = 0; ks < K; ks += KSL) {
#pragma unroll
    for (int t = 0; t < 4; ++t) {
      int flat = t * 256 + tid;
      int r = flat >> 4;
      int c4 = flat & 15;
      float4 av = *(const float4*)&A[(size_t)(rb + r) * K + ks + 4 * c4];
      *(float4*)&a_s[r][4 * c4] = av;
      float4 bv = *(const float4*)&Bw[(size_t)(cb + r) * K + ks + 4 * c4];
      *(float4*)&b_s[r][4 * c4] = bv;
    }
    __syncthreads();
#pragma unroll 4
    for (int kk = 0; kk < KSL; kk += 4) {
      float4 a4[4], b4[4];
#pragma unroll
      for (int i = 0; i < 4; ++i) a4[i] = *(const float4*)&a_s[ty + 16 * i][kk];
#pragma unroll
      for (int j = 0; j < 4; ++j) b4[j] = *(const float4*)&b_s[tx + 16 * j][kk];
#pragma unroll
      for (int i = 0; i < 4; ++i)
#pragma unroll
        for (int j = 0; j < 4; ++j)
          acc[i][j] += a4[i].x * b4[j].x + a4[i].y * b4[j].y +
                       a4[i].z * b4[j].z + a4[i].w * b4[j].w;
    }
    __syncthreads();
  }

#pragma unroll
  for (int i = 0; i < 4; ++i) {
    int r = rb + ty + 16 * i;
#pragma unroll
    for (int j = 0; j < 4; ++j) {
      int c = cb + tx + 16 * j;
      C[(size_t)r * N + c] = acc[i][j] + bias[c];
    }
  }
}

// ---------------------------------------------------------------------------
// Per-code inverse norms: one wave per embedding row.
// ---------------------------------------------------------------------------
__global__ __launch_bounds__(256) void emb_norms(
    const float* __restrict__ emb, float* __restrict__ inv_norm) {
  int row = blockIdx.x * 4 + (threadIdx.x >> 6);
  int lane = threadIdx.x & 63;
  const float* p = emb + (size_t)row * LAT;
  float s = 0.f;
#pragma unroll
  for (int t = 0; t < 4; ++t) {
    float v = p[lane + 64 * t];
    s += v * v;
  }
#pragma unroll
  for (int off = 32; off; off >>= 1) s += __shfl_xor(s, off);
  if (lane == 0) inv_norm[row] = 1.0f / sqrtf(s);
}

// ---------------------------------------------------------------------------
// Split fp32 rows (optionally scaled by inv_norm[row]) into hi/lo bf16 pairs,
// stored in MFMA-32x32x16 A/B fragment order:
//   block (tile32 = row>>5, ks16 = k>>4) holds lane l -> elem
//   [row = tile*32 + (l&31)][k = ks*16 + (l>>5)*8 + j], j=0..8 contiguous.
// dst layout: hi blocks at [0, 4MB), lo blocks at [+2097152 elems).
// ---------------------------------------------------------------------------
__global__ __launch_bounds__(256) void split_frag(
    const float* __restrict__ src, const float* __restrict__ inv_norm,
    __bf16* __restrict__ dst) {
  int gw = (blockIdx.x * 256 + threadIdx.x) >> 6;  // 0..4095
  int l = threadIdx.x & 63;
  int row = (gw >> 4) * 32 + (l & 31);
  int kb = (gw & 15) * 16 + (l >> 5) * 8;
  const float* p = src + (size_t)row * 256 + kb;
  float scale = inv_norm ? inv_norm[row] : 1.0f;
  bf16x8_t hv, lv;
#pragma unroll
  for (int j = 0; j < 8; ++j) {
    float v = p[j] * scale;
    __bf16 h = (__bf16)v;
    hv[j] = h;
    lv[j] = (__bf16)(v - (float)h);
  }
  size_t o = ((size_t)gw * 64 + l) * 8;
  *(bf16x8_t*)(dst + o) = hv;
  *(bf16x8_t*)(dst + 2097152 + o) = lv;
}

// ---------------------------------------------------------------------------
// Split-bf16 MFMA scorer with fused per-slot top-2 argmax.
// Grid: (8 code-splits, 64 row-blocks). Block: 256 thr = 4 waves.
// Block tile: 128 rows x 128 codes/chunk x 8 chunks (1024 codes), K=256 in
// 4 slices of 64. Per wave: 2 m-tiles x 2 n-tiles (32x32x16 bf16 MFMA),
// 3 MFMAs per frag pair (hi*hi + hi*lo + lo*hi). LDS 64 KB staged via
// global_load_lds width=16 from fragment-order buffers (lane-linear).
// Output: per (row, slot=csplit*2+nwave): packed (b1,idx) u64 + b2 u32.
// ---------------------------------------------------------------------------
__global__ __launch_bounds__(256, 2) void score_mfma(
    const char* __restrict__ zfrag, const char* __restrict__ efrag,
    unsigned long long* __restrict__ cand1, unsigned int* __restrict__ cand2) {
  __shared__ char lds[65536];
  const int tid = threadIdx.x;
  const int l = tid & 63;
  const int w = tid >> 6;
  const int wm = w >> 1, wn = w & 1;
  const int cb_block = blockIdx.x * 1024;
  const int rowbase = blockIdx.y * 128;

  float b1[2][16], b2[2][16];
  int i1[2][16];
#pragma unroll
  for (int i = 0; i < 2; ++i)
#pragma unroll
    for (int r = 0; r < 16; ++r) {
      b1[i][r] = -INFINITY;
      b2[i][r] = -INFINITY;
      i1[i][r] = 0;
    }

  for (int chunk = 0; chunk < 8; ++chunk) {
    f32x16_t acc[2][2];
#pragma unroll
    for (int i = 0; i < 2; ++i)
#pragma unroll
      for (int j = 0; j < 2; ++j) acc[i][j] = (f32x16_t)0.0f;

    for (int slice = 0; slice < 4; ++slice) {
      // stage 64 x 1KB chunks: A (z) chunks 0..31, B (emb) chunks 32..63
#pragma unroll
      for (int i = 0; i < 16; ++i) {
        int cidx = w * 16 + i;
        const char* src;
        if (cidx < 32) {
          int prec = cidx >> 4, mt = (cidx >> 2) & 3, ks = cidx & 3;
          int mtg = blockIdx.y * 4 + mt, ksg = slice * 4 + ks;
          src = zfrag + (size_t)prec * 4194304 +
                ((size_t)(mtg * 16 + ksg) << 10) + l * 16;
        } else {
          int j = cidx - 32;
          int prec = j >> 4, nt = (j >> 2) & 3, ks = j & 3;
          int ntg = blockIdx.x * 32 + chunk * 4 + nt, ksg = slice * 4 + ks;
          src = efrag + (size_t)prec * 4194304 +
                ((size_t)(ntg * 16 + ksg) << 10) + l * 16;
        }
        __builtin_amdgcn_global_load_lds((gu32_t*)src,
                                         (lu32_t*)(lds + cidx * 1024), 16, 0, 0);
      }
      __syncthreads();
#pragma unroll
      for (int ks = 0; ks < 4; ++ks) {
        bf16x8_t ah[2], al[2], bh[2], bl[2];
#pragma unroll
        for (int i = 0; i < 2; ++i) {
          int mt = wm * 2 + i;
          ah[i] = *(const bf16x8_t*)(lds + ((mt * 4 + ks) << 10) + l * 16);
          al[i] = *(const bf16x8_t*)(lds + (((4 + mt) * 4 + ks) << 10) + l * 16);
          int nt = wn * 2 + i;
          bh[i] = *(const bf16x8_t*)(lds + 32768 + ((nt * 4 + ks) << 10) + l * 16);
          bl[i] = *(const bf16x8_t*)(lds + 32768 + (((4 + nt) * 4 + ks) << 10) + l * 16);
        }
#pragma unroll
        for (int i = 0; i < 2; ++i)
#pragma unroll
          for (int j = 0; j < 2; ++j) {
            acc[i][j] = __builtin_amdgcn_mfma_f32_32x32x16_bf16(ah[i], bh[j], acc[i][j], 0, 0, 0);
            acc[i][j] = __builtin_amdgcn_mfma_f32_32x32x16_bf16(ah[i], bl[j], acc[i][j], 0, 0, 0);
            acc[i][j] = __builtin_amdgcn_mfma_f32_32x32x16_bf16(al[i], bh[j], acc[i][j], 0, 0, 0);
          }
      }
      __syncthreads();
    }
    // fold chunk accumulators into per-slot running top-2 (candidates ascend)
    int col = l & 31;
    int code0 = cb_block + chunk * 128 + wn * 64 + col;
#pragma unroll
    for (int i = 0; i < 2; ++i)
#pragma unroll
      for (int r = 0; r < 16; ++r) {
        float s0 = acc[i][0][r], s1 = acc[i][1][r];
        float pmax = fmaxf(s0, s1), pmin = fminf(s0, s1);
        int pidx = (s1 > s0) ? (code0 + 32) : code0;
        float ob1 = b1[i][r];
        b2[i][r] = fmaxf(fminf(ob1, pmax), fmaxf(b2[i][r], pmin));
        if (pmax > ob1) { b1[i][r] = pmax; i1[i][r] = pidx; }
      }
  }

  // cross-lane (32 cols) top-2 merge, tie -> lower idx, then write slot result
  int q = l >> 5;
  int slot = blockIdx.x * 2 + wn;
#pragma unroll
  for (int i = 0; i < 2; ++i)
#pragma unroll
    for (int r = 0; r < 16; ++r) {
      float v1 = b1[i][r], v2 = b2[i][r];
      int vi = i1[i][r];
#pragma unroll
      for (int m = 1; m < 32; m <<= 1) {
        float o1 = __shfl_xor(v1, m);
        int oi = __shfl_xor(vi, m);
        float o2 = __shfl_xor(v2, m);
        float n2v = fmaxf(fminf(v1, o1), fmaxf(v2, o2));
        if (o1 > v1 || (o1 == v1 && oi < vi)) { v1 = o1; vi = oi; }
        v2 = n2v;
      }
      if ((l & 31) == 0) {
        int row = rowbase + (wm * 2 + i) * 32 + (r & 3) + 8 * (r >> 2) + 4 * q;
        cand1[(size_t)row * 16 + slot] =
            ((unsigned long long)ford(v1) << 32) |
            (unsigned long long)(unsigned int)(NEMB - 1 - vi);
        cand2[(size_t)row * 16 + slot] = ford(v2);
      }
    }
}

// ---------------------------------------------------------------------------
// Per-row: merge 16 slots -> winner + exact global runner-up -> margin.
// Rows with margin < TAU are appended to the flag list for exact rescore.
// ---------------------------------------------------------------------------
__global__ __launch_bounds__(256) void finalize1(
    const unsigned long long* __restrict__ cand1,
    const unsigned int* __restrict__ cand2, int* __restrict__ idxi,
    unsigned int* __restrict__ flags, unsigned int* __restrict__ flag_count,
    unsigned int* __restrict__ flag_list) {
  int row = blockIdx.x * 256 + threadIdx.x;
  unsigned long long best = 0;
  unsigned int second = 0;
  int bslot = 0;
#pragma unroll
  for (int s = 0; s < 16; ++s) {
    unsigned long long v = cand1[(size_t)row * 16 + s];
    unsigned int vs = (unsigned int)(v >> 32);
    if (v > best) {
      second = (unsigned int)(best >> 32);
      best = v;
      bslot = s;
    } else if (vs > second) {
      second = vs;
    }
  }
  unsigned int r2 = cand2[(size_t)row * 16 + bslot];
  if (r2 > second) second = r2;
  float s1 = funord((unsigned int)(best >> 32));
  float s2 = funord(second);
  int idx = NEMB - 1 - (int)(best & 0xFFFFFFFFull);
  idxi[row] = idx;
  unsigned int fl = ((s1 - s2) < TAU) ? 1u : 0u;
  flags[row] = fl;
  if (fl) {
    unsigned int p = atomicAdd(flag_count, 1u);
    flag_list[p] = row;
  }
}

// ---------------------------------------------------------------------------
// Exact (fp64-accumulate) rescore of flagged rows. Block b owns 32 codes;
// loops flagged rows; per-block reduce then one packed atomicMax per row.
// ---------------------------------------------------------------------------
__global__ __launch_bounds__(256) void rescore(
    const float* __restrict__ z, const float* __restrict__ emb,
    const unsigned int* __restrict__ flag_list,
    const unsigned int* __restrict__ flag_count,
    unsigned long long* __restrict__ packed_rescore) {
  __shared__ float e_s[32][260];
  __shared__ double n2_s[32];
  __shared__ unsigned long long red[32];
  const int tid = threadIdx.x;
  const int cbase = blockIdx.x * 32;

  // stage 32 codes x 256 floats
  for (int t = tid; t < 32 * 64; t += 256) {
    int r = t >> 6, c4 = t & 63;
    float4 v = *(const float4*)&emb[(size_t)(cbase + r) * 256 + 4 * c4];
    *(float4*)&e_s[r][4 * c4] = v;
  }
  __syncthreads();

  const int code = tid >> 3, part = tid & 7;
  {
    double n2 = 0;
#pragma unroll 8
    for (int k = 0; k < 32; ++k) {
      double e = e_s[code][part * 32 + k];
      n2 += e * e;
    }
    for (int m = 1; m < 8; m <<= 1) n2 += __shfl_xor(n2, m);
    if (part == 0) n2_s[code] = n2;
  }
  __syncthreads();

  unsigned int cnt = *flag_count;
  for (unsigned int f = 0; f < cnt; ++f) {
    int row = (int)flag_list[f];
    const float* zr = z + (size_t)row * 256;
    double acc = 0;
#pragma unroll 8
    for (int k = 0; k < 32; ++k)
      acc += (double)e_s[code][part * 32 + k] * (double)zr[part * 32 + k];
    for (int m = 1; m < 8; m <<= 1) acc += __shfl_xor(acc, m);
    if (part == 0) {
      double s = acc / sqrt(n2_s[code]);
      float sf = (float)s;
      red[code] = ((unsigned long long)ford(sf) << 32) |
                  (unsigned long long)(unsigned int)(NEMB - 1 - (cbase + code));
    }
    __syncthreads();
    if (tid == 0) {
      unsigned long long b = red[0];
      for (int c = 1; c < 32; ++c)
        if (red[c] > b) b = red[c];
      atomicMax(&packed_rescore[row], b);
    }
    __syncthreads();
  }
}

// ---------------------------------------------------------------------------
// Final idx (float) + z_q gather. One wave per row.
// ---------------------------------------------------------------------------
__global__ __launch_bounds__(256) void gather_out(
    const int* __restrict__ idxi, const unsigned int* __restrict__ flags,
    const unsigned long long* __restrict__ packed_rescore,
    const float* __restrict__ emb, float* __restrict__ zq,
    float* __restrict__ idx_out) {
  int row = blockIdx.x * 4 + (threadIdx.x >> 6);
  int lane = threadIdx.x & 63;
  int idx = idxi[row];
  if (flags[row])
    idx = NEMB - 1 - (int)(packed_rescore[row] & 0xFFFFFFFFull);
  if (lane == 0) idx_out[row] = (float)idx;
  const float4* src = (const float4*)(emb + (size_t)idx * 256);
  float4* dst = (float4*)(zq + (size_t)row * 256);
  dst[lane] = src[lane];
}

// ---------------------------------------------------------------------------
extern "C" void kernel_launch(void* const* d_in, const int* in_sizes, int n_in,
                              void* d_out, int out_size, void* d_ws,
                              size_t ws_size, hipStream_t stream) {
  (void)in_sizes; (void)n_in; (void)out_size; (void)ws_size;
  const float* x     = (const float*)d_in[0];
  const float* enc_w = (const float*)d_in[1];
  const float* enc_b = (const float*)d_in[2];
  const float* emb   = (const float*)d_in[3];
  const float* dec_w = (const float*)d_in[4];
  const float* dec_b = (const float*)d_in[5];

  float* out     = (float*)d_out;
  float* x_recon = out;                               // 8192*1024
  float* z_out   = x_recon + (size_t)BATCH * IN_DIM;  // 8192*256
  float* zq_out  = z_out + (size_t)BATCH * LAT;       // 8192*256
  float* idx_out = zq_out + (size_t)BATCH * LAT;      // 8192 (as float)

  char* ws = (char*)d_ws;
  float* inv_norm = (float*)ws;                                   // 32 KB
  unsigned int* flags = (unsigned int*)(ws + 32768);              // 32 KB
  int* idxi = (int*)(ws + 65536);                                 // 32 KB
  unsigned int* flag_count = (unsigned int*)(ws + 98304);         // (zeroed)
  unsigned long long* packed_rescore =
      (unsigned long long*)(ws + 98432);                          // 64 KB (zeroed)
  unsigned int* flag_list = (unsigned int*)(ws + 163968);         // 32 KB
  unsigned long long* cand1 = (unsigned long long*)(ws + 262144); // 1 MB
  unsigned int* cand2 = (unsigned int*)(ws + 1310720);            // 512 KB
  char* zfrag = ws + 2097152;                                     // 8 MB (hi+lo)
  char* efrag = ws + 10485760;                                    // 8 MB (hi+lo)

  hipMemsetAsync(ws + 98304, 0, 128 + 65536, stream);

  // codebook norms + normalized hi/lo fragment buffers
  emb_norms<<<NEMB / 4, 256, 0, stream>>>(emb, inv_norm);
  split_frag<<<1024, 256, 0, stream>>>(emb, inv_norm, (__bf16*)efrag);

  // encoder: z = x @ enc_w^T + enc_b
  gemm_nt<<<dim3(LAT / TS, BATCH / TS), 256, 0, stream>>>(
      x, enc_w, enc_b, z_out, BATCH, LAT, IN_DIM);
  split_frag<<<1024, 256, 0, stream>>>(z_out, (const float*)nullptr,
                                       (__bf16*)zfrag);

  // fused split-bf16 MFMA score + top-2 argmax
  score_mfma<<<dim3(8, 64), 256, 0, stream>>>(zfrag, efrag, cand1, cand2);

  // winner + margin; flag tight rows
  finalize1<<<32, 256, 0, stream>>>(cand1, cand2, idxi, flags, flag_count,
                                    flag_list);

  // exact rescore of flagged rows
  rescore<<<256, 256, 0, stream>>>(z_out, emb, flag_list, flag_count,
                                   packed_rescore);

  // final idx + z_q gather
  gather_out<<<BATCH / 4, 256, 0, stream>>>(idxi, flags, packed_rescore, emb,
                                            zq_out, idx_out);

  // decoder: x_recon = z_q @ dec_w^T + dec_b
  gemm_nt<<<dim3(IN_DIM / TS, BATCH / TS), 256, 0, stream>>>(
      zq_out, dec_w, dec_b, x_recon, BATCH, IN_DIM, LAT);
}